// Round 4
// baseline (654.790 us; speedup 1.0000x reference)
//
#include <hip/hip_runtime.h>

// ReluField: out[n,c] = relu( sum_{8 corners} field[clip(fl+off)][c] * prod_d |off_d - frac_d| )
// Weight note (faithful to reference): off==0 -> frac, off==1 -> 1-frac.
//
// Strategy: counting-sort points by 32^3 spatial bucket (8^3 cells each) so
// that all touches of a field cache line happen temporally together ->
// field HBM fetch drops from ~575 MB to ~unique (~256 MB) and the sweep is
// near-sequential (z-fastest bucket order matches field layout).

#define SPATIAL 256
#define NBUCK   32768      // 32^3
#define SCAN_BLK 256
#define NAUX    128        // NBUCK / SCAN_BLK

__device__ __forceinline__ int bucket_of(float cx, float cy, float cz) {
    int ix = min(max((int)floorf(cx), 0), SPATIAL - 1);
    int iy = min(max((int)floorf(cy), 0), SPATIAL - 1);
    int iz = min(max((int)floorf(cz), 0), SPATIAL - 1);
    return ((ix >> 3) << 10) | ((iy >> 3) << 5) | (iz >> 3);
}

__global__ __launch_bounds__(256) void hist_kernel(
    const float* __restrict__ coords, int* __restrict__ hist, int n)
{
    int i = blockIdx.x * blockDim.x + threadIdx.x;
    if (i >= n) return;
    float cx = coords[3 * i + 0] * (float)SPATIAL;
    float cy = coords[3 * i + 1] * (float)SPATIAL;
    float cz = coords[3 * i + 2] * (float)SPATIAL;
    atomicAdd(&hist[bucket_of(cx, cy, cz)], 1);
}

// Level-1: per-block exclusive scan of 256 entries, block totals -> aux.
__global__ __launch_bounds__(SCAN_BLK) void scan_local(
    int* __restrict__ hist, int* __restrict__ aux)
{
    __shared__ int tmp[SCAN_BLK];
    int t = threadIdx.x;
    int base = blockIdx.x * SCAN_BLK;
    int v = hist[base + t];
    tmp[t] = v;
    __syncthreads();
    for (int off = 1; off < SCAN_BLK; off <<= 1) {
        int x = (t >= off) ? tmp[t - off] : 0;
        __syncthreads();
        tmp[t] += x;
        __syncthreads();
    }
    hist[base + t] = tmp[t] - v;                 // exclusive within block
    if (t == SCAN_BLK - 1) aux[blockIdx.x] = tmp[t];
}

// Level-2: exclusive scan of the 128 block totals (single block).
__global__ __launch_bounds__(NAUX) void scan_aux(int* __restrict__ aux)
{
    __shared__ int tmp[NAUX];
    int t = threadIdx.x;
    int v = aux[t];
    tmp[t] = v;
    __syncthreads();
    for (int off = 1; off < NAUX; off <<= 1) {
        int x = (t >= off) ? tmp[t - off] : 0;
        __syncthreads();
        tmp[t] += x;
        __syncthreads();
    }
    aux[t] = tmp[t] - v;
}

// Level-3: add block offsets back -> hist[] holds global exclusive offsets.
__global__ __launch_bounds__(SCAN_BLK) void add_offsets(
    int* __restrict__ hist, const int* __restrict__ aux)
{
    hist[blockIdx.x * SCAN_BLK + threadIdx.x] += aux[blockIdx.x];
}

// Scatter points into bucket order. sorted[pos] = (cx, cy, cz, bitcast(orig)).
__global__ __launch_bounds__(256) void scatter_kernel(
    const float* __restrict__ coords, int* __restrict__ hist,
    float4* __restrict__ sorted, int n)
{
    int i = blockIdx.x * blockDim.x + threadIdx.x;
    if (i >= n) return;
    float cx = coords[3 * i + 0] * (float)SPATIAL;
    float cy = coords[3 * i + 1] * (float)SPATIAL;
    float cz = coords[3 * i + 2] * (float)SPATIAL;
    int pos = atomicAdd(&hist[bucket_of(cx, cy, cz)], 1);
    float4 s;
    s.x = cx; s.y = cy; s.z = cz; s.w = __int_as_float(i);
    sorted[pos] = s;
}

__device__ __forceinline__ float4 interp_point(
    float cx, float cy, float cz, const float4* __restrict__ f4)
{
    const float flx = floorf(cx), fly = floorf(cy), flz = floorf(cz);
    const float fx = cx - flx, fy = cy - fly, fz = cz - flz;

    int ix0 = min(max((int)flx, 0), SPATIAL - 1);
    int iy0 = min(max((int)fly, 0), SPATIAL - 1);
    int iz0 = min(max((int)flz, 0), SPATIAL - 1);
    const int ix1 = min(ix0 + 1, SPATIAL - 1);
    const int iy1 = min(iy0 + 1, SPATIAL - 1);
    const int iz1 = min(iz0 + 1, SPATIAL - 1);

    // reference weight: off==0 -> frac, off==1 -> 1-frac
    const float wx0 = fx, wx1 = 1.0f - fx;
    const float wy0 = fy, wy1 = 1.0f - fy;
    const float wz0 = fz, wz1 = 1.0f - fz;

    const long b00 = ((long)ix0 * SPATIAL + iy0) * SPATIAL;
    const long b01 = ((long)ix0 * SPATIAL + iy1) * SPATIAL;
    const long b10 = ((long)ix1 * SPATIAL + iy0) * SPATIAL;
    const long b11 = ((long)ix1 * SPATIAL + iy1) * SPATIAL;

    const float4 v000 = f4[b00 + iz0];
    const float4 v001 = f4[b00 + iz1];
    const float4 v010 = f4[b01 + iz0];
    const float4 v011 = f4[b01 + iz1];
    const float4 v100 = f4[b10 + iz0];
    const float4 v101 = f4[b10 + iz1];
    const float4 v110 = f4[b11 + iz0];
    const float4 v111 = f4[b11 + iz1];

    const float w000 = wx0 * wy0 * wz0;
    const float w001 = wx0 * wy0 * wz1;
    const float w010 = wx0 * wy1 * wz0;
    const float w011 = wx0 * wy1 * wz1;
    const float w100 = wx1 * wy0 * wz0;
    const float w101 = wx1 * wy0 * wz1;
    const float w110 = wx1 * wy1 * wz0;
    const float w111 = wx1 * wy1 * wz1;

    float4 acc;
    acc.x = v000.x * w000; acc.y = v000.y * w000; acc.z = v000.z * w000; acc.w = v000.w * w000;
    acc.x += v001.x * w001; acc.y += v001.y * w001; acc.z += v001.z * w001; acc.w += v001.w * w001;
    acc.x += v010.x * w010; acc.y += v010.y * w010; acc.z += v010.z * w010; acc.w += v010.w * w010;
    acc.x += v011.x * w011; acc.y += v011.y * w011; acc.z += v011.z * w011; acc.w += v011.w * w011;
    acc.x += v100.x * w100; acc.y += v100.y * w100; acc.z += v100.z * w100; acc.w += v100.w * w100;
    acc.x += v101.x * w101; acc.y += v101.y * w101; acc.z += v101.z * w101; acc.w += v101.w * w101;
    acc.x += v110.x * w110; acc.y += v110.y * w110; acc.z += v110.z * w110; acc.w += v110.w * w110;
    acc.x += v111.x * w111; acc.y += v111.y * w111; acc.z += v111.z * w111; acc.w += v111.w * w111;

    acc.x = fmaxf(acc.x, 0.0f);
    acc.y = fmaxf(acc.y, 0.0f);
    acc.z = fmaxf(acc.z, 0.0f);
    acc.w = fmaxf(acc.w, 0.0f);
    return acc;
}

// Main gather in bucket-sorted order; scattered 16B store to out[orig].
__global__ __launch_bounds__(256) void gather_kernel(
    const float4* __restrict__ sorted, const float* __restrict__ field,
    float* __restrict__ out, int n)
{
    int i = blockIdx.x * blockDim.x + threadIdx.x;
    if (i >= n) return;
    float4 s = sorted[i];
    int orig = __float_as_int(s.w);
    float4 acc = interp_point(s.x, s.y, s.z,
                              reinterpret_cast<const float4*>(field));
    reinterpret_cast<float4*>(out)[orig] = acc;
}

// Fallback (no workspace): direct gather in original order.
__global__ __launch_bounds__(256) void relu_field_kernel(
    const float* __restrict__ coords, const float* __restrict__ field,
    float* __restrict__ out, int n)
{
    int i = blockIdx.x * blockDim.x + threadIdx.x;
    if (i >= n) return;
    float cx = coords[3 * i + 0] * (float)SPATIAL;
    float cy = coords[3 * i + 1] * (float)SPATIAL;
    float cz = coords[3 * i + 2] * (float)SPATIAL;
    float4 acc = interp_point(cx, cy, cz,
                              reinterpret_cast<const float4*>(field));
    reinterpret_cast<float4*>(out)[i] = acc;
}

extern "C" void kernel_launch(void* const* d_in, const int* in_sizes, int n_in,
                              void* d_out, int out_size, void* d_ws, size_t ws_size,
                              hipStream_t stream) {
    const float* coords = (const float*)d_in[0];   // [N,3] fp32
    const float* field  = (const float*)d_in[1];   // [256,256,256,4] fp32
    float* out          = (float*)d_out;           // [N,4] fp32

    const int n = in_sizes[0] / 3;
    const int block = 256;
    const int grid = (n + block - 1) / block;

    // Workspace carve-up: hist (128 KiB) | aux (512 B) | sorted (N * 16 B)
    const size_t histBytes = (size_t)NBUCK * 4;        // 131072
    const size_t auxBytes  = 512;                      // 128*4, padded
    const size_t need = histBytes + auxBytes + (size_t)n * 16;

    if (ws_size < need) {
        relu_field_kernel<<<grid, block, 0, stream>>>(coords, field, out, n);
        return;
    }

    char* w = (char*)d_ws;
    int*    hist   = (int*)w;
    int*    aux    = (int*)(w + histBytes);
    float4* sorted = (float4*)(w + histBytes + auxBytes);  // 16B-aligned

    hipMemsetAsync(hist, 0, histBytes, stream);
    hist_kernel   <<<grid, block, 0, stream>>>(coords, hist, n);
    scan_local    <<<NAUX, SCAN_BLK, 0, stream>>>(hist, aux);
    scan_aux      <<<1, NAUX, 0, stream>>>(aux);
    add_offsets   <<<NAUX, SCAN_BLK, 0, stream>>>(hist, aux);
    scatter_kernel<<<grid, block, 0, stream>>>(coords, hist, sorted, n);
    gather_kernel <<<grid, block, 0, stream>>>(sorted, field, out, n);
}

// Round 9
// 580.893 us; speedup vs baseline: 1.1272x; 1.1272x over previous
//
#include <hip/hip_runtime.h>

// ReluField: out[n,c] = relu( sum_{8 corners} field[clip(fl+off)][c] * prod_d |off_d - frac_d| )
// Weight note (faithful to reference): off==0 -> frac, off==1 -> 1-frac.
//
// Pipeline: counting-sort points into 8x16x16-cell buckets (8192 buckets),
// then one block per bucket stages the (9 x 17 x 17)-cell region (41.6 KB)
// into LDS with fully-coalesced loads and interpolates its points from LDS.
// This removes the divergent-global-gather transaction bottleneck identified
// in round 4 (sorted gather: 264 MB @ 1.66 TB/s, time ~= unsorted).

#define SPATIAL 256
// bucket = 8 x 16 x 16 cells (x,y,z); region = 9 x 17 x 17 cells
#define NBX 32
#define NBY 16
#define NBZ 16
#define NBUCK 8192          // 32*16*16
#define NREG 2601           // 9*17*17 float4
#define SCAN_BLK 256
#define NAUX 32             // NBUCK / SCAN_BLK

__device__ __forceinline__ int bucket_of(float cx, float cy, float cz) {
    int ix = min(max((int)floorf(cx), 0), SPATIAL - 1);
    int iy = min(max((int)floorf(cy), 0), SPATIAL - 1);
    int iz = min(max((int)floorf(cz), 0), SPATIAL - 1);
    return ((ix >> 3) << 8) | ((iy >> 4) << 4) | (iz >> 4);
}

__global__ __launch_bounds__(256) void hist_kernel(
    const float* __restrict__ coords, int* __restrict__ hist, int n)
{
    int i = blockIdx.x * blockDim.x + threadIdx.x;
    if (i >= n) return;
    float cx = coords[3 * i + 0] * (float)SPATIAL;
    float cy = coords[3 * i + 1] * (float)SPATIAL;
    float cz = coords[3 * i + 2] * (float)SPATIAL;
    atomicAdd(&hist[bucket_of(cx, cy, cz)], 1);
}

// Level-1: per-block exclusive scan of 256 entries, block totals -> aux.
__global__ __launch_bounds__(SCAN_BLK) void scan_local(
    int* __restrict__ hist, int* __restrict__ aux)
{
    __shared__ int tmp[SCAN_BLK];
    int t = threadIdx.x;
    int base = blockIdx.x * SCAN_BLK;
    int v = hist[base + t];
    tmp[t] = v;
    __syncthreads();
    for (int off = 1; off < SCAN_BLK; off <<= 1) {
        int x = (t >= off) ? tmp[t - off] : 0;
        __syncthreads();
        tmp[t] += x;
        __syncthreads();
    }
    hist[base + t] = tmp[t] - v;                 // exclusive within block
    if (t == SCAN_BLK - 1) aux[blockIdx.x] = tmp[t];
}

// Level-2: exclusive scan of the 32 block totals (single block).
__global__ __launch_bounds__(NAUX) void scan_aux(int* __restrict__ aux)
{
    __shared__ int tmp[NAUX];
    int t = threadIdx.x;
    int v = aux[t];
    tmp[t] = v;
    __syncthreads();
    for (int off = 1; off < NAUX; off <<= 1) {
        int x = (t >= off) ? tmp[t - off] : 0;
        __syncthreads();
        tmp[t] += x;
        __syncthreads();
    }
    aux[t] = tmp[t] - v;
}

// Level-3: add block offsets back -> hist[] holds global exclusive offsets.
__global__ __launch_bounds__(SCAN_BLK) void add_offsets(
    int* __restrict__ hist, const int* __restrict__ aux)
{
    hist[blockIdx.x * SCAN_BLK + threadIdx.x] += aux[blockIdx.x];
}

// Scatter points into bucket order. sorted[pos] = (cx, cy, cz, bitcast(orig)).
// After this kernel, hist[b] == exclusive END of bucket b (start + count).
__global__ __launch_bounds__(256) void scatter_kernel(
    const float* __restrict__ coords, int* __restrict__ hist,
    float4* __restrict__ sorted, int n)
{
    int i = blockIdx.x * blockDim.x + threadIdx.x;
    if (i >= n) return;
    float cx = coords[3 * i + 0] * (float)SPATIAL;
    float cy = coords[3 * i + 1] * (float)SPATIAL;
    float cz = coords[3 * i + 2] * (float)SPATIAL;
    int pos = atomicAdd(&hist[bucket_of(cx, cy, cz)], 1);
    float4 s;
    s.x = cx; s.y = cy; s.z = cz; s.w = __int_as_float(i);
    sorted[pos] = s;
}

// One block per bucket: stage region into LDS (coalesced), interp from LDS.
__global__ __launch_bounds__(256) void gather_staged(
    const float4* __restrict__ sorted, const int* __restrict__ hist,
    const float* __restrict__ field, float* __restrict__ out)
{
    __shared__ float4 region[NREG];     // 41,616 B
    const int b  = blockIdx.x;
    const int bx = b >> 8, by = (b >> 4) & 15, bz = b & 15;
    const int x0 = bx << 3, y0 = by << 4, z0 = bz << 4;

    const float4* __restrict__ f4 = reinterpret_cast<const float4*>(field);

    // Stage 9x17x17 cells; clamp at the +255 boundary so that local index
    // base+{1,17,289} combos reproduce the reference's clipped corners.
    for (int e = threadIdx.x; e < NREG; e += 256) {
        int dx  = e / 289;              // 289 = 17*17
        int rem = e - dx * 289;
        int dy  = rem / 17;
        int dz  = rem - dy * 17;
        int gx = min(x0 + dx, SPATIAL - 1);
        int gy = min(y0 + dy, SPATIAL - 1);
        int gz = min(z0 + dz, SPATIAL - 1);
        region[e] = f4[(((gx << 8) + gy) << 8) + gz];
    }
    __syncthreads();

    const int s  = (b == 0) ? 0 : hist[b - 1];
    const int e_ = hist[b];

    for (int p = s + (int)threadIdx.x; p < e_; p += 256) {
        const float4 pt = sorted[p];
        const float cx = pt.x, cy = pt.y, cz = pt.z;
        const int orig = __float_as_int(pt.w);

        const float flx = floorf(cx), fly = floorf(cy), flz = floorf(cz);
        const float fx = cx - flx, fy = cy - fly, fz = cz - flz;

        const int ix0 = min(max((int)flx, 0), SPATIAL - 1);
        const int iy0 = min(max((int)fly, 0), SPATIAL - 1);
        const int iz0 = min(max((int)flz, 0), SPATIAL - 1);

        const int base = ((ix0 - x0) * 17 + (iy0 - y0)) * 17 + (iz0 - z0);

        const float4 v000 = region[base];
        const float4 v001 = region[base + 1];
        const float4 v010 = region[base + 17];
        const float4 v011 = region[base + 18];
        const float4 v100 = region[base + 289];
        const float4 v101 = region[base + 290];
        const float4 v110 = region[base + 306];
        const float4 v111 = region[base + 307];

        // reference weight: off==0 -> frac, off==1 -> 1-frac
        const float wx0 = fx, wx1 = 1.0f - fx;
        const float wy0 = fy, wy1 = 1.0f - fy;
        const float wz0 = fz, wz1 = 1.0f - fz;

        const float w000 = wx0 * wy0 * wz0;
        const float w001 = wx0 * wy0 * wz1;
        const float w010 = wx0 * wy1 * wz0;
        const float w011 = wx0 * wy1 * wz1;
        const float w100 = wx1 * wy0 * wz0;
        const float w101 = wx1 * wy0 * wz1;
        const float w110 = wx1 * wy1 * wz0;
        const float w111 = wx1 * wy1 * wz1;

        float4 acc;
        acc.x = v000.x * w000; acc.y = v000.y * w000; acc.z = v000.z * w000; acc.w = v000.w * w000;
        acc.x += v001.x * w001; acc.y += v001.y * w001; acc.z += v001.z * w001; acc.w += v001.w * w001;
        acc.x += v010.x * w010; acc.y += v010.y * w010; acc.z += v010.z * w010; acc.w += v010.w * w010;
        acc.x += v011.x * w011; acc.y += v011.y * w011; acc.z += v011.z * w011; acc.w += v011.w * w011;
        acc.x += v100.x * w100; acc.y += v100.y * w100; acc.z += v100.z * w100; acc.w += v100.w * w100;
        acc.x += v101.x * w101; acc.y += v101.y * w101; acc.z += v101.z * w101; acc.w += v101.w * w101;
        acc.x += v110.x * w110; acc.y += v110.y * w110; acc.z += v110.z * w110; acc.w += v110.w * w110;
        acc.x += v111.x * w111; acc.y += v111.y * w111; acc.z += v111.z * w111; acc.w += v111.w * w111;

        acc.x = fmaxf(acc.x, 0.0f);
        acc.y = fmaxf(acc.y, 0.0f);
        acc.z = fmaxf(acc.z, 0.0f);
        acc.w = fmaxf(acc.w, 0.0f);

        reinterpret_cast<float4*>(out)[orig] = acc;
    }
}

// Fallback (no workspace): direct gather in original order.
__global__ __launch_bounds__(256) void relu_field_kernel(
    const float* __restrict__ coords, const float* __restrict__ field,
    float* __restrict__ out, int n)
{
    int i = blockIdx.x * blockDim.x + threadIdx.x;
    if (i >= n) return;
    float cx = coords[3 * i + 0] * (float)SPATIAL;
    float cy = coords[3 * i + 1] * (float)SPATIAL;
    float cz = coords[3 * i + 2] * (float)SPATIAL;

    const float flx = floorf(cx), fly = floorf(cy), flz = floorf(cz);
    const float fx = cx - flx, fy = cy - fly, fz = cz - flz;

    int ix0 = min(max((int)flx, 0), SPATIAL - 1);
    int iy0 = min(max((int)fly, 0), SPATIAL - 1);
    int iz0 = min(max((int)flz, 0), SPATIAL - 1);
    const int ix1 = min(ix0 + 1, SPATIAL - 1);
    const int iy1 = min(iy0 + 1, SPATIAL - 1);
    const int iz1 = min(iz0 + 1, SPATIAL - 1);

    const float wx0 = fx, wx1 = 1.0f - fx;
    const float wy0 = fy, wy1 = 1.0f - fy;
    const float wz0 = fz, wz1 = 1.0f - fz;

    const long b00 = ((long)ix0 * SPATIAL + iy0) * SPATIAL;
    const long b01 = ((long)ix0 * SPATIAL + iy1) * SPATIAL;
    const long b10 = ((long)ix1 * SPATIAL + iy0) * SPATIAL;
    const long b11 = ((long)ix1 * SPATIAL + iy1) * SPATIAL;

    const float4* __restrict__ f4 = reinterpret_cast<const float4*>(field);
    const float4 v000 = f4[b00 + iz0];
    const float4 v001 = f4[b00 + iz1];
    const float4 v010 = f4[b01 + iz0];
    const float4 v011 = f4[b01 + iz1];
    const float4 v100 = f4[b10 + iz0];
    const float4 v101 = f4[b10 + iz1];
    const float4 v110 = f4[b11 + iz0];
    const float4 v111 = f4[b11 + iz1];

    const float w000 = wx0 * wy0 * wz0;
    const float w001 = wx0 * wy0 * wz1;
    const float w010 = wx0 * wy1 * wz0;
    const float w011 = wx0 * wy1 * wz1;
    const float w100 = wx1 * wy0 * wz0;
    const float w101 = wx1 * wy0 * wz1;
    const float w110 = wx1 * wy1 * wz0;
    const float w111 = wx1 * wy1 * wz1;

    float4 acc;
    acc.x = v000.x * w000; acc.y = v000.y * w000; acc.z = v000.z * w000; acc.w = v000.w * w000;
    acc.x += v001.x * w001; acc.y += v001.y * w001; acc.z += v001.z * w001; acc.w += v001.w * w001;
    acc.x += v010.x * w010; acc.y += v010.y * w010; acc.z += v010.z * w010; acc.w += v010.w * w010;
    acc.x += v011.x * w011; acc.y += v011.y * w011; acc.z += v011.z * w011; acc.w += v011.w * w011;
    acc.x += v100.x * w100; acc.y += v100.y * w100; acc.z += v100.z * w100; acc.w += v100.w * w100;
    acc.x += v101.x * w101; acc.y += v101.y * w101; acc.z += v101.z * w101; acc.w += v101.w * w101;
    acc.x += v110.x * w110; acc.y += v110.y * w110; acc.z += v110.z * w110; acc.w += v110.w * w110;
    acc.x += v111.x * w111; acc.y += v111.y * w111; acc.z += v111.z * w111; acc.w += v111.w * w111;

    acc.x = fmaxf(acc.x, 0.0f);
    acc.y = fmaxf(acc.y, 0.0f);
    acc.z = fmaxf(acc.z, 0.0f);
    acc.w = fmaxf(acc.w, 0.0f);
    reinterpret_cast<float4*>(out)[i] = acc;
}

extern "C" void kernel_launch(void* const* d_in, const int* in_sizes, int n_in,
                              void* d_out, int out_size, void* d_ws, size_t ws_size,
                              hipStream_t stream) {
    const float* coords = (const float*)d_in[0];   // [N,3] fp32
    const float* field  = (const float*)d_in[1];   // [256,256,256,4] fp32
    float* out          = (float*)d_out;           // [N,4] fp32

    const int n = in_sizes[0] / 3;
    const int block = 256;
    const int grid = (n + block - 1) / block;

    // Workspace carve-up: hist (32 KiB) | aux (512 B) | sorted (N * 16 B)
    const size_t histBytes = (size_t)NBUCK * 4;
    const size_t auxBytes  = 512;
    const size_t need = histBytes + auxBytes + (size_t)n * 16;

    if (ws_size < need) {
        relu_field_kernel<<<grid, block, 0, stream>>>(coords, field, out, n);
        return;
    }

    char* w = (char*)d_ws;
    int*    hist   = (int*)w;
    int*    aux    = (int*)(w + histBytes);
    float4* sorted = (float4*)(w + histBytes + auxBytes);  // 16B-aligned

    hipMemsetAsync(hist, 0, histBytes, stream);
    hist_kernel   <<<grid, block, 0, stream>>>(coords, hist, n);
    scan_local    <<<NBUCK / SCAN_BLK, SCAN_BLK, 0, stream>>>(hist, aux);
    scan_aux      <<<1, NAUX, 0, stream>>>(aux);
    add_offsets   <<<NBUCK / SCAN_BLK, SCAN_BLK, 0, stream>>>(hist, aux);
    scatter_kernel<<<grid, block, 0, stream>>>(coords, hist, sorted, n);
    gather_staged <<<NBUCK, block, 0, stream>>>(sorted, hist, field, out);
}